// Round 4
// baseline (651.117 us; speedup 1.0000x reference)
//
#include <hip/hip_runtime.h>

// PhysicsAttention, MI355X (gfx950). N=64, C=256, T=64, V=25, H=8, d=32.
// Pipeline: convert_weights -> k0_transpose (x -> x_t bf16, c-swizzled, token-major)
//           -> phys_attn_fused (per (n,t): QKV/attn/proj, reads x_t via global_load_lds,
//              writes proj result dense to out_t == x_t buffer)
//           -> k4_finish (out_t + bproj + x residual -> out, full-line writes).

typedef short bf16x8 __attribute__((ext_vector_type(8)));
typedef short short4v __attribute__((ext_vector_type(4)));
typedef float f32x4 __attribute__((ext_vector_type(4)));

#define XT_ELEMS (64ull * 1600ull * 256ull)  // 26,214,400 bf16 = 52,428,800 B

__device__ __forceinline__ unsigned short f2bf(float f) {
  union { float f; unsigned u; } v; v.f = f;
  unsigned r = v.u + 0x7fffu + ((v.u >> 16) & 1u);
  return (unsigned short)(r >> 16);
}
__device__ __forceinline__ float bf2f(unsigned short s) {
  union { unsigned u; float f; } v; v.u = ((unsigned)s) << 16;
  return v.f;
}

__device__ __forceinline__ void gload_lds16(const void* g, void* l) {
  __builtin_amdgcn_global_load_lds(
      (const __attribute__((address_space(1))) unsigned int*)g,
      (__attribute__((address_space(3))) unsigned int*)l, 16, 0, 0);
}

// ---- pre-kernel: convert Wqkv (768x256) and Wproj (256x256) to bf16 in ws ----
__global__ void convert_weights(const float* __restrict__ wqkv,
                                const float* __restrict__ wproj,
                                unsigned short* __restrict__ wout) {
  int i = blockIdx.x * blockDim.x + threadIdx.x;
  const int total = 768 * 256 + 256 * 256;
  for (; i < total; i += gridDim.x * blockDim.x) {
    float f = (i < 768 * 256) ? wqkv[i] : wproj[i - 768 * 256];
    wout[i] = f2bf(f);
  }
}

// XOR swizzle on element index (bf16 elems): flips elem bits 3..5 by row.
#define SWZ(tok, e) ((e) ^ (((tok) & 7) << 3))

// ---- K0: x [n][c][tok] f32 -> x_t [n][tok][c-swizzled] bf16, all coalesced ----
__global__ __launch_bounds__(512)
void k0_transpose(const float* __restrict__ x, unsigned short* __restrict__ xt) {
  __shared__ unsigned short T[160 * 136];  // [tokloc][c-half], pitch 136
  int b = blockIdx.x;                      // 64 n * 2 ch * 10 tc
  int tc = b % 10, ch = (b / 10) & 1, n = b / 20;
  int tok0 = tc * 160, c0 = ch * 128;
  int tid = threadIdx.x;
  int c = c0 + (tid >> 2), tq = tid & 3;
  const float* xrow = x + ((size_t)(n * 256 + c)) * 1600 + tok0 + tq * 40;
#pragma unroll
  for (int i = 0; i < 40; i += 4) {
    float4 f = *(const float4*)(xrow + i);
    int tl = tq * 40 + i;
    int tokg = tok0 + tl;
    float vals[4] = {f.x, f.y, f.z, f.w};
#pragma unroll
    for (int j = 0; j < 4; ++j) {
      int v = (tokg + j) % 25;
      int csw = c ^ ((v & 7) << 3);  // stays within the same 128-c half
      T[(tl + j) * 136 + (csw - c0)] = f2bf(vals[j]);
    }
  }
  __syncthreads();
#pragma unroll
  for (int k = 0; k < 5; ++k) {
    int u = tid + k * 512;
    int tl = u >> 4, j = u & 15;
    bf16x8 w = *(const bf16x8*)(&T[tl * 136 + j * 8]);
    *(bf16x8*)(xt + ((size_t)n * 1600 + tok0 + tl) * 256 + c0 + j * 8) = w;
  }
}

// ---- K4: out = bf2f(out_t) + bproj + x, full-line coalesced writes ----
__global__ __launch_bounds__(512)
void k4_finish(const unsigned short* __restrict__ ot, const float* __restrict__ x,
               const float* __restrict__ bproj, float* __restrict__ out) {
  __shared__ unsigned short T[160 * 136];
  int b = blockIdx.x;
  int tc = b % 10, ch = (b / 10) & 1, n = b / 20;
  int tok0 = tc * 160, c0 = ch * 128;
  int tid = threadIdx.x;
#pragma unroll
  for (int k = 0; k < 5; ++k) {
    int u = tid + k * 512;
    int tl = u >> 4, j = u & 15;
    bf16x8 w = *(const bf16x8*)(ot + ((size_t)n * 1600 + tok0 + tl) * 256 + c0 + j * 8);
    *(bf16x8*)(&T[tl * 136 + j * 8]) = w;
  }
  __syncthreads();
  int c = c0 + (tid >> 2), tq = tid & 3;
  float bp = bproj[c];
  const float* xr = x + ((size_t)(n * 256 + c)) * 1600 + tok0 + tq * 40;
  float* orow = out + ((size_t)(n * 256 + c)) * 1600 + tok0 + tq * 40;
  int cc = c - c0;
#pragma unroll
  for (int i = 0; i < 40; i += 4) {
    float4 xv = *(const float4*)(xr + i);
    int tl = tq * 40 + i;
    float4 r;
    r.x = bf2f(T[(tl + 0) * 136 + cc]) + bp + xv.x;
    r.y = bf2f(T[(tl + 1) * 136 + cc]) + bp + xv.y;
    r.z = bf2f(T[(tl + 2) * 136 + cc]) + bp + xv.z;
    r.w = bf2f(T[(tl + 3) * 136 + cc]) + bp + xv.w;
    *(float4*)(orow + i) = r;
  }
}

__global__ __launch_bounds__(512, 4)
void phys_attn_fused(const float* __restrict__ bqkv,
                     const float* __restrict__ hop_w,
                     const float* __restrict__ hop_grid,
                     const unsigned short* __restrict__ wbf,
                     unsigned short* __restrict__ xt) {
  // LDS total: 16384+16384+16896+10240+10240+4224 = 74,368 B -> 2 blocks/CU
  __shared__ unsigned short x_tok[32 * 256];   // [tok][c] swizzled, bf16
  __shared__ unsigned short xatt[32 * 256];    // [tok][c] swizzled, bf16
  __shared__ unsigned short qk_t[32 * 264];    // [tok][q:0..127 | k:128..255]
  __shared__ unsigned short val_s[128 * 40];   // [hh*32+d][tok], pitch 40
  __shared__ unsigned short p_s[8 * 16 * 40];  // per-wave [vloc][u], pitch 40
  __shared__ float pen[32 * 33];               // hop penalty (+INF mask u>=25)

  const int tid = threadIdx.x;
  const int b = blockIdx.x;
  const int n = b >> 6, t = b & 63;
  const int w = tid >> 6;
  const int lane = tid & 63;
  const int l15 = lane & 15, lg = lane >> 4;

  const unsigned short* Wq = wbf;              // 768x256 bf16
  const unsigned short* Wp = wbf + 768 * 256;  // 256x256 bf16

  // ---- phase 0: zero ghost rows, penalty table, async-copy x_t -> LDS ----
  {
    for (int idx = tid; idx < 7 * 256; idx += 512) {
      int r = 25 + (idx >> 8);
      x_tok[r * 256 + (idx & 255)] = 0;
    }
    float hw = hop_w[0];
    for (int i = tid; i < 1024; i += 512) {
      int v = i >> 5, u = i & 31;
      float pv = (u < 25) ? ((v < 25) ? hw * hop_grid[v * 25 + u] : 0.0f)
                          : __builtin_inff();
      pen[v * 33 + u] = pv;
    }
    // 12,800 B = 25 rows x 512 B, already swizzled by K0.
    const char* src = (const char*)(xt + ((size_t)n * 1600 + t * 25) * 256);
    char* dst = (char*)x_tok;
    int base = w * 1024;  // wave-uniform LDS dest; HW adds lane*16
    gload_lds16(src + base + lane * 16, dst + base);
    int base2 = base + 8192;
    if (base2 + lane * 16 < 12800)
      gload_lds16(src + base2 + lane * 16, dst + base2);
  }
  __syncthreads();

  const float scale = 0.17677669529663687f;  // 1/sqrt(32)

  for (int g = 0; g < 2; ++g) {  // head group: heads 4g .. 4g+3
    // ---- QKV GEMM: 384 rows (q x4h, k x4h, v x4h) x 32 toks, K=256 ----
#pragma unroll
    for (int j = 0; j < 6; ++j) {
      int tIdx = w * 6 + j;          // 48 tiles over 8 waves
      int mt = tIdx >> 1, nt = tIdx & 1;
      int sec = mt >> 3;             // 0:q 1:k 2:val
      int rem = mt & 7;
      int hh = rem >> 1;             // head within group (0..3)
      int sub = rem & 1;
      int wrow0 = sec * 256 + (g * 4 + hh) * 32 + sub * 16;
      int tok = nt * 16 + l15;
      f32x4 acc = {0.f, 0.f, 0.f, 0.f};
      int arow = (wrow0 + l15) * 256 + lg * 8;
      int brow = tok * 256 + lg * 8;
#pragma unroll
      for (int ks = 0; ks < 8; ++ks) {
        bf16x8 a = *(const bf16x8*)(Wq + arow + ks * 32);
        bf16x8 bfr = *(const bf16x8*)(x_tok + SWZ(tok, brow + ks * 32));
        acc = __builtin_amdgcn_mfma_f32_16x16x32_bf16(a, bfr, acc, 0, 0, 0);
      }
      int rb = wrow0 + lg * 4;  // D rows = wrow0 + lg*4 + r, col = tok
      unsigned short h0 = f2bf(acc[0] + bqkv[rb + 0]);
      unsigned short h1 = f2bf(acc[1] + bqkv[rb + 1]);
      unsigned short h2 = f2bf(acc[2] + bqkv[rb + 2]);
      unsigned short h3 = f2bf(acc[3] + bqkv[rb + 3]);
      if (sec < 2) {
        int op = sec * 128 + hh * 32 + sub * 16 + lg * 4;
        short4v pk = {(short)h0, (short)h1, (short)h2, (short)h3};
        *(short4v*)(qk_t + tok * 264 + op) = pk;
      } else {
        int dd = hh * 32 + sub * 16 + lg * 4;
        val_s[(dd + 0) * 40 + tok] = h0;
        val_s[(dd + 1) * 40 + tok] = h1;
        val_s[(dd + 2) * 40 + tok] = h2;
        val_s[(dd + 3) * 40 + tok] = h3;
      }
    }
    __syncthreads();

    // ---- attention: wave -> (head hh, v-halftile) ----
    {
      int hh = w >> 1;
      int vbase = (w & 1) * 16;
      int hglob = g * 4 + hh;
      bf16x8 aq = *(const bf16x8*)(qk_t + (vbase + l15) * 264 + hh * 32 + lg * 8);
      f32x4 att0, att1;
      {
        f32x4 z = {0.f, 0.f, 0.f, 0.f};
        bf16x8 bk0 = *(const bf16x8*)(qk_t + (0 + l15) * 264 + 128 + hh * 32 + lg * 8);
        att0 = __builtin_amdgcn_mfma_f32_16x16x32_bf16(aq, bk0, z, 0, 0, 0);
        bf16x8 bk1 = *(const bf16x8*)(qk_t + (16 + l15) * 264 + 128 + hh * 32 + lg * 8);
        att1 = __builtin_amdgcn_mfma_f32_16x16x32_bf16(aq, bk1, z, 0, 0, 0);
      }
      int pbase = w * 640;
#pragma unroll
      for (int r = 0; r < 4; ++r) {
        int v = vbase + lg * 4 + r;
        float f0 = att0[r] * scale - pen[v * 33 + l15];
        float f1 = att1[r] * scale - pen[v * 33 + 16 + l15];
        float m = fmaxf(f0, f1);
        m = fmaxf(m, __shfl_xor(m, 1));
        m = fmaxf(m, __shfl_xor(m, 2));
        m = fmaxf(m, __shfl_xor(m, 4));
        m = fmaxf(m, __shfl_xor(m, 8));
        float e0 = __expf(f0 - m);
        float e1 = __expf(f1 - m);
        float s = e0 + e1;
        s += __shfl_xor(s, 1);
        s += __shfl_xor(s, 2);
        s += __shfl_xor(s, 4);
        s += __shfl_xor(s, 8);
        float inv = 1.0f / s;
        p_s[pbase + (lg * 4 + r) * 40 + l15] = f2bf(e0 * inv);
        p_s[pbase + (lg * 4 + r) * 40 + 16 + l15] = f2bf(e1 * inv);
      }
      bf16x8 bp = *(const bf16x8*)(p_s + pbase + l15 * 40 + lg * 8);
#pragma unroll
      for (int mt2 = 0; mt2 < 2; ++mt2) {
        bf16x8 av = *(const bf16x8*)(val_s + (hh * 32 + mt2 * 16 + l15) * 40 + lg * 8);
        f32x4 z = {0.f, 0.f, 0.f, 0.f};
        f32x4 o = __builtin_amdgcn_mfma_f32_16x16x32_bf16(av, bp, z, 0, 0, 0);
        int c0 = hglob * 32 + mt2 * 16 + lg * 4;
        int tok = vbase + l15;
        short4v pk = {(short)f2bf(o[0]), (short)f2bf(o[1]),
                      (short)f2bf(o[2]), (short)f2bf(o[3])};
        *(short4v*)(xatt + SWZ(tok, tok * 256 + c0)) = pk;
      }
    }
    __syncthreads();
  }

  // ---- output projection; write dense bf16 to out_t (== xt buffer) ----
#pragma unroll
  for (int j = 0; j < 4; ++j) {
    int tIdx = w * 4 + j;             // 32 tiles over 8 waves
    int mt = tIdx >> 1, nt = tIdx & 1;
    int tok = nt * 16 + l15;
    f32x4 acc = {0.f, 0.f, 0.f, 0.f};
    int arow = (mt * 16 + l15) * 256 + lg * 8;
    int brow = tok * 256 + lg * 8;
#pragma unroll
    for (int ks = 0; ks < 8; ++ks) {
      bf16x8 a = *(const bf16x8*)(Wp + arow + ks * 8 * 4);
      bf16x8 bfr = *(const bf16x8*)(xatt + SWZ(tok, brow + ks * 32));
      acc = __builtin_amdgcn_mfma_f32_16x16x32_bf16(a, bfr, acc, 0, 0, 0);
    }
    if (tok < 25) {
      int o0 = mt * 16 + lg * 4;
      short4v pk = {(short)f2bf(acc[0]), (short)f2bf(acc[1]),
                    (short)f2bf(acc[2]), (short)f2bf(acc[3])};
      *(short4v*)(xt + ((size_t)n * 1600 + t * 25 + tok) * 256 + o0) = pk;
    }
  }
}

extern "C" void kernel_launch(void* const* d_in, const int* in_sizes, int n_in,
                              void* d_out, int out_size, void* d_ws, size_t ws_size,
                              hipStream_t stream) {
  const float* x        = (const float*)d_in[0];
  const float* wqkv     = (const float*)d_in[1];
  const float* bqkv     = (const float*)d_in[2];
  const float* wproj    = (const float*)d_in[3];
  const float* bproj    = (const float*)d_in[4];
  const float* hop_w    = (const float*)d_in[5];
  const float* hop_grid = (const float*)d_in[6];
  float* out = (float*)d_out;

  unsigned short* xt  = (unsigned short*)d_ws;              // 52,428,800 B (x_t, reused as out_t)
  unsigned short* wbf = (unsigned short*)d_ws + XT_ELEMS;   // +524,288 B

  convert_weights<<<dim3(256), dim3(256), 0, stream>>>(wqkv, wproj, wbf);
  k0_transpose<<<dim3(1280), dim3(512), 0, stream>>>(x, xt);
  phys_attn_fused<<<dim3(64 * 64), dim3(512), 0, stream>>>(
      bqkv, hop_w, hop_grid, wbf, xt);
  k4_finish<<<dim3(1280), dim3(512), 0, stream>>>(xt, x, bproj, out);
}